// Round 4
// baseline (240.813 us; speedup 1.0000x reference)
//
#include <hip/hip_runtime.h>

// ---------------------------------------------------------------------------
// Types / helpers
// ---------------------------------------------------------------------------
typedef __attribute__((ext_vector_type(8))) short bf16x8;   // 8 bf16 = 4 VGPR
typedef __attribute__((ext_vector_type(4))) short bf16x4;   // 8 bytes
typedef __attribute__((ext_vector_type(4))) float f32x4;    // MFMA acc

static __device__ __forceinline__ short f2bf(float f) {
    union { float f; unsigned u; } v; v.f = f;
    unsigned r = v.u + 0x7fffu + ((v.u >> 16) & 1u);   // RNE
    return (short)(r >> 16);
}

// async global->LDS, 16B per lane; lds dest MUST be base + lane*16 (m97/m104)
static __device__ __forceinline__ void async_copy16(const short* g, short* l) {
    __builtin_amdgcn_global_load_lds((const __attribute__((address_space(1))) void*)g,
                                     (__attribute__((address_space(3))) void*)l,
                                     16, 0, 0);
}

#define HEADS 16
#define DHEAD 64
#define NSEQ  2048
#define DIM   1024
#define BATCH 2
#define ROWS  (BATCH * NSEQ)          // 4096
#define NQKV  (3 * HEADS * DHEAD)     // 3072

// ---------------------------------------------------------------------------
// RMSNorm: xn = x / max(||x||,eps) * sqrt(dim) * gamma   (fp32 in, bf16 out)
// ---------------------------------------------------------------------------
__global__ __launch_bounds__(256) void rmsnorm_kernel(const float* __restrict__ x,
                                                      const float* __restrict__ gamma,
                                                      short* __restrict__ xn) {
    const int row = blockIdx.x;
    const int t = threadIdx.x;
    const float4 v = ((const float4*)(x + (size_t)row * DIM))[t];
    float s = v.x * v.x + v.y * v.y + v.z * v.z + v.w * v.w;
#pragma unroll
    for (int off = 32; off > 0; off >>= 1) s += __shfl_down(s, off, 64);
    __shared__ float part[4];
    if ((t & 63) == 0) part[t >> 6] = s;
    __syncthreads();
    const float tot = part[0] + part[1] + part[2] + part[3];
    const float scale = 32.0f / fmaxf(sqrtf(tot), 1e-12f);   // sqrt(1024)=32
    const float4 g = ((const float4*)gamma)[t];
    bf16x4 o;
    o[0] = f2bf(v.x * scale * g.x);
    o[1] = f2bf(v.y * scale * g.y);
    o[2] = f2bf(v.z * scale * g.z);
    o[3] = f2bf(v.w * scale * g.w);
    *(bf16x4*)(xn + (size_t)row * DIM + t * 4) = o;
}

// ---------------------------------------------------------------------------
// Transpose + cast: in fp32 [R][C] -> out bf16 [C][R]  (32x32 LDS tiles)
// ---------------------------------------------------------------------------
__global__ __launch_bounds__(256) void transpose_cast(const float* __restrict__ in,
                                                      short* __restrict__ out,
                                                      int R, int C) {
    __shared__ float tile[32][33];
    const int tx = threadIdx.x & 31, ty = threadIdx.x >> 5;   // ty 0..7
    const int gx = blockIdx.x * 32, gy = blockIdx.y * 32;
#pragma unroll
    for (int i = 0; i < 4; ++i)
        tile[ty + i * 8][tx] = in[(size_t)(gy + ty + i * 8) * C + gx + tx];
    __syncthreads();
#pragma unroll
    for (int i = 0; i < 4; ++i)
        out[(size_t)(gx + ty + i * 8) * R + gy + tx] = f2bf(tile[tx][ty + i * 8]);
}

// ---------------------------------------------------------------------------
// Transpose V: v [32][2048][64] bf16 -> vt [32][64][2048] bf16
// ---------------------------------------------------------------------------
__global__ __launch_bounds__(256) void transpose_v(const short* __restrict__ v,
                                                   short* __restrict__ vt) {
    const int bh = blockIdx.y;
    const int n0 = blockIdx.x * 64;
    __shared__ short tile[64 * 72];
    const int r = threadIdx.x >> 3;          // 0..31
    const int c8 = (threadIdx.x & 7) * 8;    // 0..56
#pragma unroll
    for (int p = 0; p < 2; ++p)
        *(bf16x8*)&tile[(p * 32 + r) * 72 + c8] =
            *(const bf16x8*)&v[((size_t)bh * NSEQ + n0 + p * 32 + r) * DHEAD + c8];
    __syncthreads();
#pragma unroll
    for (int p = 0; p < 2; ++p) {
        const int d = p * 32 + r;
        bf16x8 o;
#pragma unroll
        for (int j = 0; j < 8; ++j) o[j] = tile[(c8 + j) * 72 + d];
        *(bf16x8*)&vt[((size_t)bh * DHEAD + d) * NSEQ + n0 + c8] = o;
    }
}

// ---------------------------------------------------------------------------
// GEMM: C[M x N] = A[M x K] * Bt[N x K]^T, bf16 in, fp32 acc.
// Tile = (WM*MT*16) x (WN*NT*16); 4 waves arranged WM x WN;
// global_load_lds width-16 staging into unpadded row-major 32-col LDS tiles.
// MODE 0: scatter to q/k/v [3][b*h][n][d] bf16, scale q by d^-0.5.
// MODE 1: fp32 row-major output.
// ---------------------------------------------------------------------------
template <int MODE, int MT, int NT, int WM, int WN>
__global__ __launch_bounds__(256) void gemm_bt(const short* __restrict__ A,
                                               const short* __restrict__ Bt,
                                               void* __restrict__ Cout,
                                               int K, int N) {
    constexpr int TM = WM * MT * 16;
    constexpr int TN = WN * NT * 16;
    __shared__ alignas(16) short lds_a[TM * 32];   // unpadded: global_load_lds contract
    __shared__ alignas(16) short lds_b[TN * 32];
    const int tid = threadIdx.x;
    const int lane = tid & 63, wid = tid >> 6;
    const int quad = lane >> 4, l16 = lane & 15;
    const int wm = wid / WN, wn = wid % WN;
    const int mb = blockIdx.y * TM, nb = blockIdx.x * TN;

    f32x4 acc[MT][NT];
#pragma unroll
    for (int i = 0; i < MT; ++i)
#pragma unroll
        for (int j = 0; j < NT; ++j) acc[i][j] = (f32x4){0.f, 0.f, 0.f, 0.f};

    // staging: per call, wave w covers 16 rows; lane l -> row +l/4, col (l&3)*8
    const int lr = lane >> 2;
    const int lc = (lane & 3) * 8;

    for (int kb = 0; kb < K; kb += 32) {
        __syncthreads();   // all waves done reading previous tile
#pragma unroll
        for (int c = 0; c < TM / 64; ++c) {
            const int row = c * 64 + wid * 16 + lr;
            async_copy16(&A[(size_t)(mb + row) * K + kb + lc], &lds_a[row * 32 + lc]);
        }
#pragma unroll
        for (int c = 0; c < TN / 64; ++c) {
            const int row = c * 64 + wid * 16 + lr;
            async_copy16(&Bt[(size_t)(nb + row) * K + kb + lc], &lds_b[row * 32 + lc]);
        }
        __syncthreads();   // compiler drains vmcnt before barrier
        bf16x8 af[MT], bfr[NT];
#pragma unroll
        for (int mt = 0; mt < MT; ++mt)
            af[mt] = *(const bf16x8*)&lds_a[(wm * MT * 16 + mt * 16 + l16) * 32 + quad * 8];
#pragma unroll
        for (int nt = 0; nt < NT; ++nt)
            bfr[nt] = *(const bf16x8*)&lds_b[(wn * NT * 16 + nt * 16 + l16) * 32 + quad * 8];
#pragma unroll
        for (int mt = 0; mt < MT; ++mt)
#pragma unroll
            for (int nt = 0; nt < NT; ++nt)
                acc[mt][nt] = __builtin_amdgcn_mfma_f32_16x16x32_bf16(af[mt], bfr[nt],
                                                                      acc[mt][nt], 0, 0, 0);
    }

#pragma unroll
    for (int mt = 0; mt < MT; ++mt) {
#pragma unroll
        for (int nt = 0; nt < NT; ++nt) {
#pragma unroll
            for (int r = 0; r < 4; ++r) {
                const int grow = mb + wm * MT * 16 + mt * 16 + quad * 4 + r;
                const int gcol = nb + wn * NT * 16 + nt * 16 + l16;
                const float val = acc[mt][nt][r];
                if (MODE == 0) {
                    const int s3 = gcol >> 10, rem = gcol & 1023;
                    const int hh = rem >> 6, dd = rem & 63;
                    const int bb = grow >> 11, npos = grow & 2047;
                    const float vq = (s3 == 0) ? val * 0.125f : val;   // q * d^-0.5
                    ((short*)Cout)[(size_t)((s3 * 32 + bb * 16 + hh) * 2048 + npos) * 64 + dd] =
                        f2bf(vq);
                } else {
                    ((float*)Cout)[(size_t)grow * N + gcol] = val;
                }
            }
        }
    }
}

// ---------------------------------------------------------------------------
// Causal flash attention, S^T formulation, zero block barriers.
// q,k: [32][2048][64] bf16 (q pre-scaled). vt: [32][64][2048] bf16.
// One 32-query chunk per wave; 2048 waves / 512 blocks (2 blocks/CU).
// Blocks are chunk-uniform (4 waves = 4 heads, same qc) and dispatched
// heavy-first (qc = 63 - gw/32) so long waves start at t=0.
// ---------------------------------------------------------------------------
__global__ __launch_bounds__(256, 2) void attn_kernel(const short* __restrict__ qg,
                                                      const short* __restrict__ kg,
                                                      const short* __restrict__ vtg,
                                                      short* __restrict__ og) {
    const int tid = threadIdx.x;
    const int wid = tid >> 6, lane = tid & 63;
    const int quad = lane >> 4, l16 = lane & 15;
    const int gw = blockIdx.x * 4 + wid;        // 0..2047
    const int bh = gw & 31;                     // head (uniform spread per chunk band)
    const int qc = 63 - (gw >> 5);              // chunk: heavy chunks dispatched first
    const size_t base = (size_t)bh * (NSEQ * DHEAD);
    const int bb = bh >> 4, hh = bh & 15;

    __shared__ alignas(16) short pbuf[4][32 * 72];   // wave-private P transform
    short* const pb = pbuf[wid];

    const int qbase = qc * 32;
    const int ntiles = (qc >> 1) + 1;           // 64-key tiles (causal bound)

    // Q fragments (B-operand): lane n=l16 -> query qbase+qn*16+l16, k=quad*8+j
    bf16x8 qf[2][2];
#pragma unroll
    for (int qn = 0; qn < 2; ++qn)
#pragma unroll
        for (int kh = 0; kh < 2; ++kh)
            qf[qn][kh] = *(const bf16x8*)&qg[base + (size_t)(qbase + qn * 16 + l16) * DHEAD +
                                            kh * 32 + quad * 8];

    float mi[2], li[2];
    f32x4 accO[2][4];
#pragma unroll
    for (int qn = 0; qn < 2; ++qn) {
        mi[qn] = -3.0e38f; li[qn] = 0.f;
#pragma unroll
        for (int nc = 0; nc < 4; ++nc) accO[qn][nc] = (f32x4){0.f, 0.f, 0.f, 0.f};
    }

    // K fragments (A-operand) for tile 0; prefetched each iteration
    bf16x8 kf[4][2];
#pragma unroll
    for (int m = 0; m < 4; ++m) {
        const short* kr = &kg[base + (size_t)(m * 16 + l16) * DHEAD];
        kf[m][0] = *(const bf16x8*)&kr[quad * 8];
        kf[m][1] = *(const bf16x8*)&kr[32 + quad * 8];
    }

    for (int t = 0; t < ntiles; ++t) {
        const int kb = t * 64;

        // ---- S^T = K Q^T : 16 MFMAs ----
        f32x4 sf[2][4];
#pragma unroll
        for (int m = 0; m < 4; ++m)
#pragma unroll
            for (int qn = 0; qn < 2; ++qn) {
                f32x4 z = (f32x4){0.f, 0.f, 0.f, 0.f};
                z = __builtin_amdgcn_mfma_f32_16x16x32_bf16(kf[m][0], qf[qn][0], z, 0, 0, 0);
                sf[qn][m] = __builtin_amdgcn_mfma_f32_16x16x32_bf16(kf[m][1], qf[qn][1], z,
                                                                    0, 0, 0);
            }

        // ---- prefetch next K tile (hidden behind softmax + PV) ----
        if (t + 1 < ntiles) {
#pragma unroll
            for (int m = 0; m < 4; ++m) {
                const short* kr = &kg[base + (size_t)(kb + 64 + m * 16 + l16) * DHEAD];
                kf[m][0] = *(const bf16x8*)&kr[quad * 8];
                kf[m][1] = *(const bf16x8*)&kr[32 + quad * 8];
            }
        }
        // ---- V^T fragments for this tile (issued before softmax) ----
        bf16x8 vf[4][2];
#pragma unroll
        for (int nc = 0; nc < 4; ++nc) {
            const short* vr = &vtg[base + (size_t)(nc * 16 + l16) * NSEQ + kb];
            vf[nc][0] = *(const bf16x8*)&vr[quad * 8];
            vf[nc][1] = *(const bf16x8*)&vr[32 + quad * 8];
        }

        // ---- causal mask (diagonal tile only; wave-uniform branch) ----
        if (kb + 64 > qbase) {
#pragma unroll
            for (int qn = 0; qn < 2; ++qn) {
                const int myq = qbase + qn * 16 + l16;
#pragma unroll
                for (int m = 0; m < 4; ++m)
#pragma unroll
                    for (int r = 0; r < 4; ++r)
                        if (kb + m * 16 + quad * 4 + r > myq) sf[qn][m][r] = -3.0e38f;
            }
        }

        // ---- online softmax: per-lane column = one query ----
#pragma unroll
        for (int qn = 0; qn < 2; ++qn) {
            f32x4 t4;
#pragma unroll
            for (int e = 0; e < 4; ++e)
                t4[e] = fmaxf(fmaxf(sf[qn][0][e], sf[qn][1][e]),
                              fmaxf(sf[qn][2][e], sf[qn][3][e]));
            float rm = fmaxf(fmaxf(t4[0], t4[1]), fmaxf(t4[2], t4[3]));
            rm = fmaxf(rm, __shfl_xor(rm, 16, 64));
            rm = fmaxf(rm, __shfl_xor(rm, 32, 64));
            const float nm = fmaxf(mi[qn], rm);
            const float al = __expf(mi[qn] - nm);
            mi[qn] = nm;
            float rs = 0.f;
#pragma unroll
            for (int m = 0; m < 4; ++m)
#pragma unroll
                for (int r = 0; r < 4; ++r) {
                    const float p = __expf(sf[qn][m][r] - nm);
                    sf[qn][m][r] = p;
                    rs += p;
                }
            rs += __shfl_xor(rs, 16, 64);
            rs += __shfl_xor(rs, 32, 64);
            li[qn] = li[qn] * al + rs;
#pragma unroll
            for (int nc = 0; nc < 4; ++nc)
#pragma unroll
                for (int r = 0; r < 4; ++r) accO[qn][nc][r] *= al;

            // pack P row (query l16): keys m*16+quad*4..+3 -> b64 LDS writes
#pragma unroll
            for (int m = 0; m < 4; ++m) {
                bf16x4 pw;
#pragma unroll
                for (int r = 0; r < 4; ++r) pw[r] = f2bf(sf[qn][m][r]);
                *(bf16x4*)&pb[(qn * 16 + l16) * 72 + m * 16 + quad * 4] = pw;
            }
        }

        // ---- B-fragments of P (same-wave LDS RAW, lgkmcnt-ordered) ----
        bf16x8 pf[2][2];
#pragma unroll
        for (int qn = 0; qn < 2; ++qn)
#pragma unroll
            for (int kh = 0; kh < 2; ++kh)
                pf[qn][kh] = *(const bf16x8*)&pb[(qn * 16 + l16) * 72 + kh * 32 + quad * 8];

        // ---- O^T += V^T P : 16 MFMAs ----
#pragma unroll
        for (int nc = 0; nc < 4; ++nc)
#pragma unroll
            for (int qn = 0; qn < 2; ++qn) {
                accO[qn][nc] = __builtin_amdgcn_mfma_f32_16x16x32_bf16(vf[nc][0], pf[qn][0],
                                                                      accO[qn][nc], 0, 0, 0);
                accO[qn][nc] = __builtin_amdgcn_mfma_f32_16x16x32_bf16(vf[nc][1], pf[qn][1],
                                                                      accO[qn][nc], 0, 0, 0);
            }
    }

    // ---- epilogue: O^T lane = query l16; d = nc*16+quad*4+r -> b64 stores ----
#pragma unroll
    for (int qn = 0; qn < 2; ++qn) {
        const float inv = 1.0f / li[qn];
        const int npos = qbase + qn * 16 + l16;
#pragma unroll
        for (int nc = 0; nc < 4; ++nc) {
            bf16x4 ow;
#pragma unroll
            for (int r = 0; r < 4; ++r) ow[r] = f2bf(accO[qn][nc][r] * inv);
            *(bf16x4*)&og[(size_t)(bb * 2048 + npos) * 1024 + hh * 64 + nc * 16 + quad * 4] = ow;
        }
    }
}

// ---------------------------------------------------------------------------
// Launch
// ---------------------------------------------------------------------------
extern "C" void kernel_launch(void* const* d_in, const int* in_sizes, int n_in,
                              void* d_out, int out_size, void* d_ws, size_t ws_size,
                              hipStream_t stream) {
    const float* x     = (const float*)d_in[0];
    const float* gamma = (const float*)d_in[1];
    const float* w_qkv = (const float*)d_in[2];
    const float* w_out = (const float*)d_in[3];
    float* out = (float*)d_out;
    char* ws = (char*)d_ws;

    short* xn     = (short*)(ws);                    //  8 MB (dead after gemm<0>)
    short* vt     = (short*)(ws);                    //  8 MB (reuses xn)
    short* wqkvT  = (short*)(ws + 8388608);          //  6 MB
    short* woutT  = (short*)(ws + 14680064);         //  2 MB
    short* q      = (short*)(ws + 16777216);         // 24 MB: [3][32][2048][64]
    short* k      = q + 32 * 2048 * 64;
    short* v      = k + 32 * 2048 * 64;
    short* attn   = (short*)(ws + 41943040);         //  8 MB

    transpose_cast<<<dim3(NQKV / 32, DIM / 32), 256, 0, stream>>>(w_qkv, wqkvT, DIM, NQKV);
    transpose_cast<<<dim3(DIM / 32, DIM / 32), 256, 0, stream>>>(w_out, woutT, DIM, DIM);
    rmsnorm_kernel<<<ROWS, 256, 0, stream>>>(x, gamma, xn);
    // 128x128 tile: 24x32 = 768 blocks (3/CU)
    gemm_bt<0, 4, 4, 2, 2><<<dim3(NQKV / 128, ROWS / 128), 256, 0, stream>>>(xn, wqkvT, q,
                                                                             DIM, NQKV);
    transpose_v<<<dim3(NSEQ / 64, 32), 256, 0, stream>>>(v, vt);
    attn_kernel<<<512, 256, 0, stream>>>(q, k, vt, attn);
    // 128x64 tile: 16x32 = 512 blocks (2/CU) -- was 256 (1/CU, latency-bound)
    gemm_bt<1, 2, 4, 4, 1><<<dim3(DIM / 64, ROWS / 128), 256, 0, stream>>>(attn, woutT, out,
                                                                           DIM, DIM);
}

// Round 5
// 219.985 us; speedup vs baseline: 1.0947x; 1.0947x over previous
//
#include <hip/hip_runtime.h>

// ---------------------------------------------------------------------------
// Types / helpers
// ---------------------------------------------------------------------------
typedef __attribute__((ext_vector_type(8))) short bf16x8;   // 8 bf16 = 4 VGPR
typedef __attribute__((ext_vector_type(4))) short bf16x4;   // 8 bytes
typedef __attribute__((ext_vector_type(4))) float f32x4;    // MFMA acc

static __device__ __forceinline__ short f2bf(float f) {
    union { float f; unsigned u; } v; v.f = f;
    unsigned r = v.u + 0x7fffu + ((v.u >> 16) & 1u);   // RNE
    return (short)(r >> 16);
}

// async global->LDS, 16B per lane; lds dest MUST be base + lane*16 (m97/m104)
static __device__ __forceinline__ void async_copy16(const short* g, short* l) {
    __builtin_amdgcn_global_load_lds((const __attribute__((address_space(1))) void*)g,
                                     (__attribute__((address_space(3))) void*)l,
                                     16, 0, 0);
}

#define HEADS 16
#define DHEAD 64
#define NSEQ  2048
#define DIM   1024
#define BATCH 2
#define ROWS  (BATCH * NSEQ)          // 4096
#define NQKV  (3 * HEADS * DHEAD)     // 3072

// ---------------------------------------------------------------------------
// RMSNorm: xn = x / max(||x||,eps) * sqrt(dim) * gamma   (fp32 in, bf16 out)
// ---------------------------------------------------------------------------
__global__ __launch_bounds__(256) void rmsnorm_kernel(const float* __restrict__ x,
                                                      const float* __restrict__ gamma,
                                                      short* __restrict__ xn) {
    const int row = blockIdx.x;
    const int t = threadIdx.x;
    const float4 v = ((const float4*)(x + (size_t)row * DIM))[t];
    float s = v.x * v.x + v.y * v.y + v.z * v.z + v.w * v.w;
#pragma unroll
    for (int off = 32; off > 0; off >>= 1) s += __shfl_down(s, off, 64);
    __shared__ float part[4];
    if ((t & 63) == 0) part[t >> 6] = s;
    __syncthreads();
    const float tot = part[0] + part[1] + part[2] + part[3];
    const float scale = 32.0f / fmaxf(sqrtf(tot), 1e-12f);   // sqrt(1024)=32
    const float4 g = ((const float4*)gamma)[t];
    bf16x4 o;
    o[0] = f2bf(v.x * scale * g.x);
    o[1] = f2bf(v.y * scale * g.y);
    o[2] = f2bf(v.z * scale * g.z);
    o[3] = f2bf(v.w * scale * g.w);
    *(bf16x4*)(xn + (size_t)row * DIM + t * 4) = o;
}

// ---------------------------------------------------------------------------
// Transpose + cast: in fp32 [R][C] -> out bf16 [C][R]  (32x32 LDS tiles)
// ---------------------------------------------------------------------------
__global__ __launch_bounds__(256) void transpose_cast(const float* __restrict__ in,
                                                      short* __restrict__ out,
                                                      int R, int C) {
    __shared__ float tile[32][33];
    const int tx = threadIdx.x & 31, ty = threadIdx.x >> 5;   // ty 0..7
    const int gx = blockIdx.x * 32, gy = blockIdx.y * 32;
#pragma unroll
    for (int i = 0; i < 4; ++i)
        tile[ty + i * 8][tx] = in[(size_t)(gy + ty + i * 8) * C + gx + tx];
    __syncthreads();
#pragma unroll
    for (int i = 0; i < 4; ++i)
        out[(size_t)(gx + ty + i * 8) * R + gy + tx] = f2bf(tile[tx][ty + i * 8]);
}

// ---------------------------------------------------------------------------
// Transpose V: v [32][2048][64] bf16 -> vt [32][64][2048] bf16
// ---------------------------------------------------------------------------
__global__ __launch_bounds__(256) void transpose_v(const short* __restrict__ v,
                                                   short* __restrict__ vt) {
    const int bh = blockIdx.y;
    const int n0 = blockIdx.x * 64;
    __shared__ short tile[64 * 72];
    const int r = threadIdx.x >> 3;          // 0..31
    const int c8 = (threadIdx.x & 7) * 8;    // 0..56
#pragma unroll
    for (int p = 0; p < 2; ++p)
        *(bf16x8*)&tile[(p * 32 + r) * 72 + c8] =
            *(const bf16x8*)&v[((size_t)bh * NSEQ + n0 + p * 32 + r) * DHEAD + c8];
    __syncthreads();
#pragma unroll
    for (int p = 0; p < 2; ++p) {
        const int d = p * 32 + r;
        bf16x8 o;
#pragma unroll
        for (int j = 0; j < 8; ++j) o[j] = tile[(c8 + j) * 72 + d];
        *(bf16x8*)&vt[((size_t)bh * DHEAD + d) * NSEQ + n0 + c8] = o;
    }
}

// ---------------------------------------------------------------------------
// GEMM: C[M x N] = A[M x K] * Bt[N x K]^T, bf16 in, fp32 acc.
// Tile = (WM*MT*16) x (WN*NT*16); 4 waves arranged WM x WN;
// global_load_lds width-16 staging into unpadded row-major 32-col LDS tiles.
// MODE 0: scatter to q/k/v [3][b*h][n][d] bf16, scale q by d^-0.5.
// MODE 1: fp32 row-major output.
// ---------------------------------------------------------------------------
template <int MODE, int MT, int NT, int WM, int WN>
__global__ __launch_bounds__(256) void gemm_bt(const short* __restrict__ A,
                                               const short* __restrict__ Bt,
                                               void* __restrict__ Cout,
                                               int K, int N) {
    constexpr int TM = WM * MT * 16;
    constexpr int TN = WN * NT * 16;
    __shared__ alignas(16) short lds_a[TM * 32];   // unpadded: global_load_lds contract
    __shared__ alignas(16) short lds_b[TN * 32];
    const int tid = threadIdx.x;
    const int lane = tid & 63, wid = tid >> 6;
    const int quad = lane >> 4, l16 = lane & 15;
    const int wm = wid / WN, wn = wid % WN;
    const int mb = blockIdx.y * TM, nb = blockIdx.x * TN;

    f32x4 acc[MT][NT];
#pragma unroll
    for (int i = 0; i < MT; ++i)
#pragma unroll
        for (int j = 0; j < NT; ++j) acc[i][j] = (f32x4){0.f, 0.f, 0.f, 0.f};

    // staging: per call, wave w covers 16 rows; lane l -> row +l/4, col (l&3)*8
    const int lr = lane >> 2;
    const int lc = (lane & 3) * 8;

    for (int kb = 0; kb < K; kb += 32) {
        __syncthreads();   // all waves done reading previous tile
#pragma unroll
        for (int c = 0; c < TM / 64; ++c) {
            const int row = c * 64 + wid * 16 + lr;
            async_copy16(&A[(size_t)(mb + row) * K + kb + lc], &lds_a[row * 32 + lc]);
        }
#pragma unroll
        for (int c = 0; c < TN / 64; ++c) {
            const int row = c * 64 + wid * 16 + lr;
            async_copy16(&Bt[(size_t)(nb + row) * K + kb + lc], &lds_b[row * 32 + lc]);
        }
        __syncthreads();   // compiler drains vmcnt before barrier
        bf16x8 af[MT], bfr[NT];
#pragma unroll
        for (int mt = 0; mt < MT; ++mt)
            af[mt] = *(const bf16x8*)&lds_a[(wm * MT * 16 + mt * 16 + l16) * 32 + quad * 8];
#pragma unroll
        for (int nt = 0; nt < NT; ++nt)
            bfr[nt] = *(const bf16x8*)&lds_b[(wn * NT * 16 + nt * 16 + l16) * 32 + quad * 8];
#pragma unroll
        for (int mt = 0; mt < MT; ++mt)
#pragma unroll
            for (int nt = 0; nt < NT; ++nt)
                acc[mt][nt] = __builtin_amdgcn_mfma_f32_16x16x32_bf16(af[mt], bfr[nt],
                                                                      acc[mt][nt], 0, 0, 0);
    }

#pragma unroll
    for (int mt = 0; mt < MT; ++mt) {
#pragma unroll
        for (int nt = 0; nt < NT; ++nt) {
#pragma unroll
            for (int r = 0; r < 4; ++r) {
                const int grow = mb + wm * MT * 16 + mt * 16 + quad * 4 + r;
                const int gcol = nb + wn * NT * 16 + nt * 16 + l16;
                const float val = acc[mt][nt][r];
                if (MODE == 0) {
                    const int s3 = gcol >> 10, rem = gcol & 1023;
                    const int hh = rem >> 6, dd = rem & 63;
                    const int bb = grow >> 11, npos = grow & 2047;
                    const float vq = (s3 == 0) ? val * 0.125f : val;   // q * d^-0.5
                    ((short*)Cout)[(size_t)((s3 * 32 + bb * 16 + hh) * 2048 + npos) * 64 + dd] =
                        f2bf(vq);
                } else {
                    ((float*)Cout)[(size_t)grow * N + gcol] = val;
                }
            }
        }
    }
}

// ---------------------------------------------------------------------------
// Causal flash attention, S^T formulation, key-split across wave pairs.
// q,k: [32][2048][64] bf16 (q pre-scaled). vt: [32][64][2048] bf16.
// Each (bh, 32-query chunk) task is handled by TWO waves: wave half=0 takes
// even 64-key tiles, half=1 takes odd tiles (halves the 33-tile critical path
// of the heaviest chunk). Partial (m, l, O) merged exactly via LDS + one
// __syncthreads outside all loops. 2048 tasks -> 1024 blocks, heavy-first.
// ---------------------------------------------------------------------------
__global__ __launch_bounds__(256, 1) void attn_kernel(const short* __restrict__ qg,
                                                      const short* __restrict__ kg,
                                                      const short* __restrict__ vtg,
                                                      short* __restrict__ og) {
    const int tid = threadIdx.x;
    const int wid = tid >> 6, lane = tid & 63;
    const int quad = lane >> 4, l16 = lane & 15;
    const int tix = wid >> 1;                   // task slot in block (0,1)
    const int half = wid & 1;                   // key-interleave phase
    const int task = blockIdx.x * 2 + tix;      // 0..2047
    const int bh = task & 31;
    const int qc = 63 - (task >> 5);            // heavy chunks dispatched first
    const size_t base = (size_t)bh * (NSEQ * DHEAD);
    const int bb = bh >> 4, hh = bh & 15;

    __shared__ alignas(16) short pbuf[4][32 * 72];    // wave-private P transform
    __shared__ alignas(16) float obuf[2][32 * 68];    // B-half partial O (row pad 68: 16B-aligned, 2-way banks)
    __shared__ float mlbuf[2][2][2][16];              // [task][m|l][qn][l16]
    short* const pb = pbuf[wid];

    const int qbase = qc * 32;
    const int ntiles = (qc >> 1) + 1;           // 64-key tiles (causal bound)

    // Q fragments (B-operand): lane n=l16 -> query qbase+qn*16+l16, k=quad*8+j
    bf16x8 qf[2][2];
#pragma unroll
    for (int qn = 0; qn < 2; ++qn)
#pragma unroll
        for (int kh = 0; kh < 2; ++kh)
            qf[qn][kh] = *(const bf16x8*)&qg[base + (size_t)(qbase + qn * 16 + l16) * DHEAD +
                                            kh * 32 + quad * 8];

    float mi[2], li[2];
    f32x4 accO[2][4];
#pragma unroll
    for (int qn = 0; qn < 2; ++qn) {
        mi[qn] = -3.0e38f; li[qn] = 0.f;
#pragma unroll
        for (int nc = 0; nc < 4; ++nc) accO[qn][nc] = (f32x4){0.f, 0.f, 0.f, 0.f};
    }

    // K fragments (A-operand) for this wave's first tile; prefetched ahead
    bf16x8 kf[4][2];
#pragma unroll
    for (int m = 0; m < 4; ++m) {
        const short* kr = &kg[base + (size_t)(half * 64 + m * 16 + l16) * DHEAD];
        kf[m][0] = *(const bf16x8*)&kr[quad * 8];
        kf[m][1] = *(const bf16x8*)&kr[32 + quad * 8];
    }

    for (int t = half; t < ntiles; t += 2) {
        const int kb = t * 64;

        // ---- S^T = K Q^T : 16 MFMAs ----
        f32x4 sf[2][4];
#pragma unroll
        for (int m = 0; m < 4; ++m)
#pragma unroll
            for (int qn = 0; qn < 2; ++qn) {
                f32x4 z = (f32x4){0.f, 0.f, 0.f, 0.f};
                z = __builtin_amdgcn_mfma_f32_16x16x32_bf16(kf[m][0], qf[qn][0], z, 0, 0, 0);
                sf[qn][m] = __builtin_amdgcn_mfma_f32_16x16x32_bf16(kf[m][1], qf[qn][1], z,
                                                                    0, 0, 0);
            }

        // ---- prefetch this wave's next K tile (t+2), hidden behind softmax+PV ----
        if (t + 2 < ntiles) {
#pragma unroll
            for (int m = 0; m < 4; ++m) {
                const short* kr = &kg[base + (size_t)(kb + 128 + m * 16 + l16) * DHEAD];
                kf[m][0] = *(const bf16x8*)&kr[quad * 8];
                kf[m][1] = *(const bf16x8*)&kr[32 + quad * 8];
            }
        }
        // ---- V^T fragments for this tile (issued before softmax) ----
        bf16x8 vf[4][2];
#pragma unroll
        for (int nc = 0; nc < 4; ++nc) {
            const short* vr = &vtg[base + (size_t)(nc * 16 + l16) * NSEQ + kb];
            vf[nc][0] = *(const bf16x8*)&vr[quad * 8];
            vf[nc][1] = *(const bf16x8*)&vr[32 + quad * 8];
        }

        // ---- causal mask (diagonal tile only; wave-uniform branch) ----
        if (kb + 64 > qbase) {
#pragma unroll
            for (int qn = 0; qn < 2; ++qn) {
                const int myq = qbase + qn * 16 + l16;
#pragma unroll
                for (int m = 0; m < 4; ++m)
#pragma unroll
                    for (int r = 0; r < 4; ++r)
                        if (kb + m * 16 + quad * 4 + r > myq) sf[qn][m][r] = -3.0e38f;
            }
        }

        // ---- online softmax: per-lane column = one query ----
#pragma unroll
        for (int qn = 0; qn < 2; ++qn) {
            f32x4 t4;
#pragma unroll
            for (int e = 0; e < 4; ++e)
                t4[e] = fmaxf(fmaxf(sf[qn][0][e], sf[qn][1][e]),
                              fmaxf(sf[qn][2][e], sf[qn][3][e]));
            float rm = fmaxf(fmaxf(t4[0], t4[1]), fmaxf(t4[2], t4[3]));
            rm = fmaxf(rm, __shfl_xor(rm, 16, 64));
            rm = fmaxf(rm, __shfl_xor(rm, 32, 64));
            const float nm = fmaxf(mi[qn], rm);
            const float al = __expf(mi[qn] - nm);
            mi[qn] = nm;
            float rs = 0.f;
#pragma unroll
            for (int m = 0; m < 4; ++m)
#pragma unroll
                for (int r = 0; r < 4; ++r) {
                    const float p = __expf(sf[qn][m][r] - nm);
                    sf[qn][m][r] = p;
                    rs += p;
                }
            rs += __shfl_xor(rs, 16, 64);
            rs += __shfl_xor(rs, 32, 64);
            li[qn] = li[qn] * al + rs;
#pragma unroll
            for (int nc = 0; nc < 4; ++nc)
#pragma unroll
                for (int r = 0; r < 4; ++r) accO[qn][nc][r] *= al;

            // pack P row (query l16): keys m*16+quad*4..+3 -> b64 LDS writes
#pragma unroll
            for (int m = 0; m < 4; ++m) {
                bf16x4 pw;
#pragma unroll
                for (int r = 0; r < 4; ++r) pw[r] = f2bf(sf[qn][m][r]);
                *(bf16x4*)&pb[(qn * 16 + l16) * 72 + m * 16 + quad * 4] = pw;
            }
        }

        // ---- B-fragments of P (same-wave LDS RAW, lgkmcnt-ordered) ----
        bf16x8 pf[2][2];
#pragma unroll
        for (int qn = 0; qn < 2; ++qn)
#pragma unroll
            for (int kh = 0; kh < 2; ++kh)
                pf[qn][kh] = *(const bf16x8*)&pb[(qn * 16 + l16) * 72 + kh * 32 + quad * 8];

        // ---- O^T += V^T P : 16 MFMAs ----
#pragma unroll
        for (int nc = 0; nc < 4; ++nc)
#pragma unroll
            for (int qn = 0; qn < 2; ++qn) {
                accO[qn][nc] = __builtin_amdgcn_mfma_f32_16x16x32_bf16(vf[nc][0], pf[qn][0],
                                                                      accO[qn][nc], 0, 0, 0);
                accO[qn][nc] = __builtin_amdgcn_mfma_f32_16x16x32_bf16(vf[nc][1], pf[qn][1],
                                                                      accO[qn][nc], 0, 0, 0);
            }
    }

    // ---- pair merge: B half publishes (m, l, O); A half combines + stores ----
    if (half == 1) {
        if (quad == 0) {
#pragma unroll
            for (int qn = 0; qn < 2; ++qn) {
                mlbuf[tix][0][qn][l16] = mi[qn];
                mlbuf[tix][1][qn][l16] = li[qn];
            }
        }
#pragma unroll
        for (int qn = 0; qn < 2; ++qn)
#pragma unroll
            for (int nc = 0; nc < 4; ++nc)
                *(f32x4*)&obuf[tix][(qn * 16 + l16) * 68 + nc * 16 + quad * 4] = accO[qn][nc];
    }
    __syncthreads();   // single block barrier, outside all loops
    if (half == 0) {
#pragma unroll
        for (int qn = 0; qn < 2; ++qn) {
            const float mB = mlbuf[tix][0][qn][l16];
            const float lB = mlbuf[tix][1][qn][l16];
            const float M  = fmaxf(mi[qn], mB);
            const float eA = __expf(mi[qn] - M);
            const float eB = __expf(mB - M);      // 0 when B half had no tiles
            const float inv = 1.0f / (li[qn] * eA + lB * eB);
            const int npos = qbase + qn * 16 + l16;
#pragma unroll
            for (int nc = 0; nc < 4; ++nc) {
                const f32x4 oB =
                    *(const f32x4*)&obuf[tix][(qn * 16 + l16) * 68 + nc * 16 + quad * 4];
                bf16x4 ow;
#pragma unroll
                for (int r = 0; r < 4; ++r)
                    ow[r] = f2bf((accO[qn][nc][r] * eA + oB[r] * eB) * inv);
                *(bf16x4*)&og[(size_t)(bb * 2048 + npos) * 1024 + hh * 64 + nc * 16 + quad * 4] =
                    ow;
            }
        }
    }
}

// ---------------------------------------------------------------------------
// Launch
// ---------------------------------------------------------------------------
extern "C" void kernel_launch(void* const* d_in, const int* in_sizes, int n_in,
                              void* d_out, int out_size, void* d_ws, size_t ws_size,
                              hipStream_t stream) {
    const float* x     = (const float*)d_in[0];
    const float* gamma = (const float*)d_in[1];
    const float* w_qkv = (const float*)d_in[2];
    const float* w_out = (const float*)d_in[3];
    float* out = (float*)d_out;
    char* ws = (char*)d_ws;

    short* xn     = (short*)(ws);                    //  8 MB (dead after gemm<0>)
    short* vt     = (short*)(ws);                    //  8 MB (reuses xn)
    short* wqkvT  = (short*)(ws + 8388608);          //  6 MB
    short* woutT  = (short*)(ws + 14680064);         //  2 MB
    short* q      = (short*)(ws + 16777216);         // 24 MB: [3][32][2048][64]
    short* k      = q + 32 * 2048 * 64;
    short* v      = k + 32 * 2048 * 64;
    short* attn   = (short*)(ws + 41943040);         //  8 MB

    transpose_cast<<<dim3(NQKV / 32, DIM / 32), 256, 0, stream>>>(w_qkv, wqkvT, DIM, NQKV);
    transpose_cast<<<dim3(DIM / 32, DIM / 32), 256, 0, stream>>>(w_out, woutT, DIM, DIM);
    rmsnorm_kernel<<<ROWS, 256, 0, stream>>>(x, gamma, xn);
    // 128x128 tile: 24x32 = 768 blocks (3/CU)
    gemm_bt<0, 4, 4, 2, 2><<<dim3(NQKV / 128, ROWS / 128), 256, 0, stream>>>(xn, wqkvT, q,
                                                                             DIM, NQKV);
    transpose_v<<<dim3(NSEQ / 64, 32), 256, 0, stream>>>(v, vt);
    // 2048 tasks x 2 key-split waves = 4096 waves / 1024 blocks
    attn_kernel<<<1024, 256, 0, stream>>>(q, k, vt, attn);
    // 128x64 tile: 16x32 = 512 blocks (2/CU)
    gemm_bt<1, 2, 4, 4, 1><<<dim3(DIM / 64, ROWS / 128), 256, 0, stream>>>(attn, woutT, out,
                                                                           DIM, DIM);
}

// Round 6
// 214.551 us; speedup vs baseline: 1.1224x; 1.0253x over previous
//
#include <hip/hip_runtime.h>

// ---------------------------------------------------------------------------
// Types / helpers
// ---------------------------------------------------------------------------
typedef __attribute__((ext_vector_type(8))) short bf16x8;   // 8 bf16 = 4 VGPR
typedef __attribute__((ext_vector_type(4))) short bf16x4;   // 8 bytes
typedef __attribute__((ext_vector_type(4))) float f32x4;    // MFMA acc

static __device__ __forceinline__ short f2bf(float f) {
    union { float f; unsigned u; } v; v.f = f;
    unsigned r = v.u + 0x7fffu + ((v.u >> 16) & 1u);   // RNE
    return (short)(r >> 16);
}

// async global->LDS, 16B per lane; lds dest MUST be base + lane*16 (m97/m104)
static __device__ __forceinline__ void async_copy16(const short* g, short* l) {
    __builtin_amdgcn_global_load_lds((const __attribute__((address_space(1))) void*)g,
                                     (__attribute__((address_space(3))) void*)l,
                                     16, 0, 0);
}

#define HEADS 16
#define DHEAD 64
#define NSEQ  2048
#define DIM   1024
#define BATCH 2
#define ROWS  (BATCH * NSEQ)          // 4096
#define NQKV  (3 * HEADS * DHEAD)     // 3072

// ---------------------------------------------------------------------------
// RMSNorm: xn = x / max(||x||,eps) * sqrt(dim) * gamma   (fp32 in, bf16 out)
// ---------------------------------------------------------------------------
__global__ __launch_bounds__(256) void rmsnorm_kernel(const float* __restrict__ x,
                                                      const float* __restrict__ gamma,
                                                      short* __restrict__ xn) {
    const int row = blockIdx.x;
    const int t = threadIdx.x;
    const float4 v = ((const float4*)(x + (size_t)row * DIM))[t];
    float s = v.x * v.x + v.y * v.y + v.z * v.z + v.w * v.w;
#pragma unroll
    for (int off = 32; off > 0; off >>= 1) s += __shfl_down(s, off, 64);
    __shared__ float part[4];
    if ((t & 63) == 0) part[t >> 6] = s;
    __syncthreads();
    const float tot = part[0] + part[1] + part[2] + part[3];
    const float scale = 32.0f / fmaxf(sqrtf(tot), 1e-12f);   // sqrt(1024)=32
    const float4 g = ((const float4*)gamma)[t];
    bf16x4 o;
    o[0] = f2bf(v.x * scale * g.x);
    o[1] = f2bf(v.y * scale * g.y);
    o[2] = f2bf(v.z * scale * g.z);
    o[3] = f2bf(v.w * scale * g.w);
    *(bf16x4*)(xn + (size_t)row * DIM + t * 4) = o;
}

// ---------------------------------------------------------------------------
// Transpose + cast: in fp32 [R][C] -> out bf16 [C][R]  (32x32 LDS tiles)
// ---------------------------------------------------------------------------
__global__ __launch_bounds__(256) void transpose_cast(const float* __restrict__ in,
                                                      short* __restrict__ out,
                                                      int R, int C) {
    __shared__ float tile[32][33];
    const int tx = threadIdx.x & 31, ty = threadIdx.x >> 5;   // ty 0..7
    const int gx = blockIdx.x * 32, gy = blockIdx.y * 32;
#pragma unroll
    for (int i = 0; i < 4; ++i)
        tile[ty + i * 8][tx] = in[(size_t)(gy + ty + i * 8) * C + gx + tx];
    __syncthreads();
#pragma unroll
    for (int i = 0; i < 4; ++i)
        out[(size_t)(gx + ty + i * 8) * R + gy + tx] = f2bf(tile[tx][ty + i * 8]);
}

// ---------------------------------------------------------------------------
// GEMM: C[M x N] = A[M x K] * Bt[N x K]^T, bf16 in, fp32 acc.
// Tile = (WM*MT*16) x (WN*NT*16); 4 waves arranged WM x WN;
// global_load_lds width-16 staging into unpadded row-major 32-col LDS tiles.
// MODE 0: scatter q/k into [s][b*h][n][d] bf16 (q scaled d^-0.5);
//         V is written TRANSPOSED to vtOut [b*h][d][n] via b64 stores
//         (the 4-row r-run of the C-layout is contiguous in n).
// MODE 1: fp32 row-major output.
// ---------------------------------------------------------------------------
template <int MODE, int MT, int NT, int WM, int WN>
__global__ __launch_bounds__(256) void gemm_bt(const short* __restrict__ A,
                                               const short* __restrict__ Bt,
                                               void* __restrict__ Cout,
                                               short* __restrict__ vtOut,
                                               int K, int N) {
    constexpr int TM = WM * MT * 16;
    constexpr int TN = WN * NT * 16;
    __shared__ alignas(16) short lds_a[TM * 32];   // unpadded: global_load_lds contract
    __shared__ alignas(16) short lds_b[TN * 32];
    const int tid = threadIdx.x;
    const int lane = tid & 63, wid = tid >> 6;
    const int quad = lane >> 4, l16 = lane & 15;
    const int wm = wid / WN, wn = wid % WN;
    const int mb = blockIdx.y * TM, nb = blockIdx.x * TN;

    f32x4 acc[MT][NT];
#pragma unroll
    for (int i = 0; i < MT; ++i)
#pragma unroll
        for (int j = 0; j < NT; ++j) acc[i][j] = (f32x4){0.f, 0.f, 0.f, 0.f};

    // staging: per call, wave w covers 16 rows; lane l -> row +l/4, col (l&3)*8
    const int lr = lane >> 2;
    const int lc = (lane & 3) * 8;

    for (int kb = 0; kb < K; kb += 32) {
        __syncthreads();   // all waves done reading previous tile
#pragma unroll
        for (int c = 0; c < TM / 64; ++c) {
            const int row = c * 64 + wid * 16 + lr;
            async_copy16(&A[(size_t)(mb + row) * K + kb + lc], &lds_a[row * 32 + lc]);
        }
#pragma unroll
        for (int c = 0; c < TN / 64; ++c) {
            const int row = c * 64 + wid * 16 + lr;
            async_copy16(&Bt[(size_t)(nb + row) * K + kb + lc], &lds_b[row * 32 + lc]);
        }
        __syncthreads();   // compiler drains vmcnt before barrier
        bf16x8 af[MT], bfr[NT];
#pragma unroll
        for (int mt = 0; mt < MT; ++mt)
            af[mt] = *(const bf16x8*)&lds_a[(wm * MT * 16 + mt * 16 + l16) * 32 + quad * 8];
#pragma unroll
        for (int nt = 0; nt < NT; ++nt)
            bfr[nt] = *(const bf16x8*)&lds_b[(wn * NT * 16 + nt * 16 + l16) * 32 + quad * 8];
#pragma unroll
        for (int mt = 0; mt < MT; ++mt)
#pragma unroll
            for (int nt = 0; nt < NT; ++nt)
                acc[mt][nt] = __builtin_amdgcn_mfma_f32_16x16x32_bf16(af[mt], bfr[nt],
                                                                      acc[mt][nt], 0, 0, 0);
    }

#pragma unroll
    for (int mt = 0; mt < MT; ++mt) {
#pragma unroll
        for (int nt = 0; nt < NT; ++nt) {
            const int grow0 = mb + wm * MT * 16 + mt * 16 + quad * 4;   // r-run base row
            const int gcol  = nb + wn * NT * 16 + nt * 16 + l16;
            if (MODE == 0) {
                const int s3 = gcol >> 10, rem = gcol & 1023;   // s3 wave-uniform per nt
                const int hh = rem >> 6, dd = rem & 63;
                const int bb = grow0 >> 11, npos0 = grow0 & 2047;
                if (s3 == 2) {
                    // vt[bh][d][n]: r-run contiguous in n -> one b64 store
                    bf16x4 vw;
#pragma unroll
                    for (int r = 0; r < 4; ++r) vw[r] = f2bf(acc[mt][nt][r]);
                    *(bf16x4*)&vtOut[((size_t)(bb * 16 + hh) * 64 + dd) * 2048 + npos0] = vw;
                } else {
                    const float sc = (s3 == 0) ? 0.125f : 1.0f;   // q * d^-0.5
#pragma unroll
                    for (int r = 0; r < 4; ++r)
                        ((short*)Cout)[(size_t)((s3 * 32 + bb * 16 + hh) * 2048 + npos0 + r) * 64 +
                                       dd] = f2bf(acc[mt][nt][r] * sc);
                }
            } else {
#pragma unroll
                for (int r = 0; r < 4; ++r)
                    ((float*)Cout)[(size_t)(grow0 + r) * N + gcol] = acc[mt][nt][r];
            }
        }
    }
}

// ---------------------------------------------------------------------------
// Causal flash attention, S^T formulation, 4-way key split per task.
// q,k: [32][2048][64] bf16 (q pre-scaled). vt: [32][64][2048] bf16.
// Block = one (bh, 32-query chunk) task; wave w handles 64-key tiles
// t = w, w+4, ... (heaviest wave: 8 tiles vs 17 in the 2-way split).
// Waves 1-3 publish partial (m,l,O) to LDS (disjoint from pbuf, so a single
// __syncthreads outside all loops suffices); wave 0 merges exactly.
// 2048 blocks, heavy-first so the 32 heavy tasks spread over 32 CUs at t=0.
// ---------------------------------------------------------------------------
__global__ __launch_bounds__(256, 1) void attn_kernel(const short* __restrict__ qg,
                                                      const short* __restrict__ kg,
                                                      const short* __restrict__ vtg,
                                                      short* __restrict__ og) {
    const int tid = threadIdx.x;
    const int wid = tid >> 6, lane = tid & 63;
    const int quad = lane >> 4, l16 = lane & 15;
    const int task = blockIdx.x;                // 0..2047
    const int bh = task & 31;
    const int qc = 63 - (task >> 5);            // heavy chunks dispatched first
    const size_t base = (size_t)bh * (NSEQ * DHEAD);
    const int bb = bh >> 4, hh = bh & 15;

    __shared__ alignas(16) short pbuf[4][32 * 72];    // wave-private P transform (18.4 KB)
    __shared__ alignas(16) float obuf[3][32 * 68];    // waves 1-3 partial O (26.1 KB)
    __shared__ float mlbuf[3][2][2][16];              // [slot][m|l][qn][l16]
    short* const pb = pbuf[wid];

    const int qbase = qc * 32;
    const int ntiles = (qc >> 1) + 1;           // 64-key tiles (causal bound)

    // Q fragments (B-operand): lane n=l16 -> query qbase+qn*16+l16, k=quad*8+j
    bf16x8 qf[2][2];
#pragma unroll
    for (int qn = 0; qn < 2; ++qn)
#pragma unroll
        for (int kh = 0; kh < 2; ++kh)
            qf[qn][kh] = *(const bf16x8*)&qg[base + (size_t)(qbase + qn * 16 + l16) * DHEAD +
                                            kh * 32 + quad * 8];

    float mi[2], li[2];
    f32x4 accO[2][4];
#pragma unroll
    for (int qn = 0; qn < 2; ++qn) {
        mi[qn] = -3.0e38f; li[qn] = 0.f;
#pragma unroll
        for (int nc = 0; nc < 4; ++nc) accO[qn][nc] = (f32x4){0.f, 0.f, 0.f, 0.f};
    }

    // K fragments (A-operand) for this wave's first tile (t = wid)
    bf16x8 kf[4][2];
#pragma unroll
    for (int m = 0; m < 4; ++m) {
        const short* kr = &kg[base + (size_t)(wid * 64 + m * 16 + l16) * DHEAD];
        kf[m][0] = *(const bf16x8*)&kr[quad * 8];
        kf[m][1] = *(const bf16x8*)&kr[32 + quad * 8];
    }

    for (int t = wid; t < ntiles; t += 4) {
        const int kb = t * 64;

        // ---- S^T = K Q^T : 16 MFMAs ----
        f32x4 sf[2][4];
#pragma unroll
        for (int m = 0; m < 4; ++m)
#pragma unroll
            for (int qn = 0; qn < 2; ++qn) {
                f32x4 z = (f32x4){0.f, 0.f, 0.f, 0.f};
                z = __builtin_amdgcn_mfma_f32_16x16x32_bf16(kf[m][0], qf[qn][0], z, 0, 0, 0);
                sf[qn][m] = __builtin_amdgcn_mfma_f32_16x16x32_bf16(kf[m][1], qf[qn][1], z,
                                                                    0, 0, 0);
            }

        // ---- prefetch this wave's next K tile (t+4), hidden behind softmax+PV ----
        if (t + 4 < ntiles) {
#pragma unroll
            for (int m = 0; m < 4; ++m) {
                const short* kr = &kg[base + (size_t)(kb + 256 + m * 16 + l16) * DHEAD];
                kf[m][0] = *(const bf16x8*)&kr[quad * 8];
                kf[m][1] = *(const bf16x8*)&kr[32 + quad * 8];
            }
        }
        // ---- V^T fragments for this tile (issued before softmax) ----
        bf16x8 vf[4][2];
#pragma unroll
        for (int nc = 0; nc < 4; ++nc) {
            const short* vr = &vtg[base + (size_t)(nc * 16 + l16) * NSEQ + kb];
            vf[nc][0] = *(const bf16x8*)&vr[quad * 8];
            vf[nc][1] = *(const bf16x8*)&vr[32 + quad * 8];
        }

        // ---- causal mask (diagonal tile only; wave-uniform branch) ----
        if (kb + 64 > qbase) {
#pragma unroll
            for (int qn = 0; qn < 2; ++qn) {
                const int myq = qbase + qn * 16 + l16;
#pragma unroll
                for (int m = 0; m < 4; ++m)
#pragma unroll
                    for (int r = 0; r < 4; ++r)
                        if (kb + m * 16 + quad * 4 + r > myq) sf[qn][m][r] = -3.0e38f;
            }
        }

        // ---- online softmax: per-lane column = one query ----
#pragma unroll
        for (int qn = 0; qn < 2; ++qn) {
            f32x4 t4;
#pragma unroll
            for (int e = 0; e < 4; ++e)
                t4[e] = fmaxf(fmaxf(sf[qn][0][e], sf[qn][1][e]),
                              fmaxf(sf[qn][2][e], sf[qn][3][e]));
            float rm = fmaxf(fmaxf(t4[0], t4[1]), fmaxf(t4[2], t4[3]));
            rm = fmaxf(rm, __shfl_xor(rm, 16, 64));
            rm = fmaxf(rm, __shfl_xor(rm, 32, 64));
            const float nm = fmaxf(mi[qn], rm);
            const float al = __expf(mi[qn] - nm);
            mi[qn] = nm;
            float rs = 0.f;
#pragma unroll
            for (int m = 0; m < 4; ++m)
#pragma unroll
                for (int r = 0; r < 4; ++r) {
                    const float p = __expf(sf[qn][m][r] - nm);
                    sf[qn][m][r] = p;
                    rs += p;
                }
            rs += __shfl_xor(rs, 16, 64);
            rs += __shfl_xor(rs, 32, 64);
            li[qn] = li[qn] * al + rs;
#pragma unroll
            for (int nc = 0; nc < 4; ++nc)
#pragma unroll
                for (int r = 0; r < 4; ++r) accO[qn][nc][r] *= al;

            // pack P row (query l16): keys m*16+quad*4..+3 -> b64 LDS writes
#pragma unroll
            for (int m = 0; m < 4; ++m) {
                bf16x4 pw;
#pragma unroll
                for (int r = 0; r < 4; ++r) pw[r] = f2bf(sf[qn][m][r]);
                *(bf16x4*)&pb[(qn * 16 + l16) * 72 + m * 16 + quad * 4] = pw;
            }
        }

        // ---- B-fragments of P (same-wave LDS RAW, lgkmcnt-ordered) ----
        bf16x8 pf[2][2];
#pragma unroll
        for (int qn = 0; qn < 2; ++qn)
#pragma unroll
            for (int kh = 0; kh < 2; ++kh)
                pf[qn][kh] = *(const bf16x8*)&pb[(qn * 16 + l16) * 72 + kh * 32 + quad * 8];

        // ---- O^T += V^T P : 16 MFMAs ----
#pragma unroll
        for (int nc = 0; nc < 4; ++nc)
#pragma unroll
            for (int qn = 0; qn < 2; ++qn) {
                accO[qn][nc] = __builtin_amdgcn_mfma_f32_16x16x32_bf16(vf[nc][0], pf[qn][0],
                                                                      accO[qn][nc], 0, 0, 0);
                accO[qn][nc] = __builtin_amdgcn_mfma_f32_16x16x32_bf16(vf[nc][1], pf[qn][1],
                                                                      accO[qn][nc], 0, 0, 0);
            }
    }

    // ---- waves 1-3 publish partial (m, l, O); disjoint LDS from pbuf ----
    if (wid > 0) {
        const int slot = wid - 1;
        if (quad == 0) {
#pragma unroll
            for (int qn = 0; qn < 2; ++qn) {
                mlbuf[slot][0][qn][l16] = mi[qn];
                mlbuf[slot][1][qn][l16] = li[qn];
            }
        }
#pragma unroll
        for (int qn = 0; qn < 2; ++qn)
#pragma unroll
            for (int nc = 0; nc < 4; ++nc)
                *(f32x4*)&obuf[slot][(qn * 16 + l16) * 68 + nc * 16 + quad * 4] = accO[qn][nc];
    }
    __syncthreads();   // single block barrier, outside all loops
    // ---- wave 0 merges 4 partials exactly and stores ----
    if (wid == 0) {
#pragma unroll
        for (int qn = 0; qn < 2; ++qn) {
            float M = mi[qn];
#pragma unroll
            for (int s = 0; s < 3; ++s) M = fmaxf(M, mlbuf[s][0][qn][l16]);
            const float e0 = __expf(mi[qn] - M);
            float es[3];
            float L = li[qn] * e0;
#pragma unroll
            for (int s = 0; s < 3; ++s) {
                es[s] = __expf(mlbuf[s][0][qn][l16] - M);   // 0 for empty waves
                L += mlbuf[s][1][qn][l16] * es[s];
            }
            const float inv = 1.0f / L;
            const int npos = qbase + qn * 16 + l16;
#pragma unroll
            for (int nc = 0; nc < 4; ++nc) {
                f32x4 o;
#pragma unroll
                for (int r = 0; r < 4; ++r) o[r] = accO[qn][nc][r] * e0;
#pragma unroll
                for (int s = 0; s < 3; ++s) {
                    const f32x4 oS =
                        *(const f32x4*)&obuf[s][(qn * 16 + l16) * 68 + nc * 16 + quad * 4];
#pragma unroll
                    for (int r = 0; r < 4; ++r) o[r] += oS[r] * es[s];
                }
                bf16x4 ow;
#pragma unroll
                for (int r = 0; r < 4; ++r) ow[r] = f2bf(o[r] * inv);
                *(bf16x4*)&og[(size_t)(bb * 2048 + npos) * 1024 + hh * 64 + nc * 16 + quad * 4] =
                    ow;
            }
        }
    }
}

// ---------------------------------------------------------------------------
// Launch
// ---------------------------------------------------------------------------
extern "C" void kernel_launch(void* const* d_in, const int* in_sizes, int n_in,
                              void* d_out, int out_size, void* d_ws, size_t ws_size,
                              hipStream_t stream) {
    const float* x     = (const float*)d_in[0];
    const float* gamma = (const float*)d_in[1];
    const float* w_qkv = (const float*)d_in[2];
    const float* w_out = (const float*)d_in[3];
    float* out = (float*)d_out;
    char* ws = (char*)d_ws;

    short* xn     = (short*)(ws);                    //  8 MB
    short* wqkvT  = (short*)(ws + 8388608);          //  6 MB
    short* woutT  = (short*)(ws + 14680064);         //  2 MB
    short* q      = (short*)(ws + 16777216);         //  8 MB: [32][2048][64]
    short* k      = q + 32 * 2048 * 64;              //  8 MB: [32][2048][64]
    short* vt     = k + 32 * 2048 * 64;              //  8 MB: [32][64][2048] (written by gemm<0>)
    short* attn   = (short*)(ws + 41943040);         //  8 MB

    transpose_cast<<<dim3(NQKV / 32, DIM / 32), 256, 0, stream>>>(w_qkv, wqkvT, DIM, NQKV);
    transpose_cast<<<dim3(DIM / 32, DIM / 32), 256, 0, stream>>>(w_out, woutT, DIM, DIM);
    rmsnorm_kernel<<<ROWS, 256, 0, stream>>>(x, gamma, xn);
    // 128x128 tile: 24x32 = 768 blocks (3/CU); V written transposed in epilogue
    gemm_bt<0, 4, 4, 2, 2><<<dim3(NQKV / 128, ROWS / 128), 256, 0, stream>>>(xn, wqkvT, q, vt,
                                                                             DIM, NQKV);
    // 2048 tasks, one per block; 4-way key split inside the block
    attn_kernel<<<2048, 256, 0, stream>>>(q, k, vt, attn);
    // 128x64 tile: 16x32 = 512 blocks (2/CU)
    gemm_bt<1, 2, 4, 4, 1><<<dim3(DIM / 64, ROWS / 128), 256, 0, stream>>>(attn, woutT, out,
                                                                           nullptr, DIM, DIM);
}